// Round 1
// baseline (231.761 us; speedup 1.0000x reference)
//
#include <hip/hip_runtime.h>
#include <math.h>

// CBOW hierarchical-softmax loss — R4: latency attack.
//   B=65536, C=10, D=18, E=128.
//   loss[b] = -sum_d log( p_d + 1e-9 ), p_d = (code==1) ? s_d : 1 - s_d,
//   s_d = sigmoid(u_d . v), v = mean_c in_embed[ctx[b,c]].
//
// R1 lesson: p MUST be computed literally as fp32 reference does (s, then
// 1-s) including cancellation at s==1.0f; precise expf/logf (not __expf).
// R2 lesson: VALU-bound work identified; R3 halved it (half-wave d-split).
// R4 theory: counters show NO saturated pipe (VALU 52%, HBM 44%, occ 71%)
//   -> latency-bound. Two causes visible in disasm-level evidence:
//   (a) 23 of 37 VMEM instructions per wave are wave-uniform index loads
//       (same address in all lanes) clogging the vector-memory pipe;
//   (b) VGPR_Count=36 proves <=2 gather results ever in flight (14 float4
//       in flight would need 56 VGPRs) — gathers consumed in dep order.
// Fix: readfirstlane(b) -> SGPR, so all 46 index loads become SMEM scalar
// loads; then issue ALL 14 row-gathers into named register arrays before
// consuming any. Float op order kept bit-identical to R3 (absmax 0.0).

constexpr int Bn = 65536;
constexpr int Cn = 10;
constexpr int Dn = 18;
constexpr float EPS = 1e-9f;

__global__ __launch_bounds__(256) void cbow_hs_kernel(
    const int* __restrict__ ctx,          // [B,C]
    const int* __restrict__ nodes,        // [B,D]
    const int* __restrict__ codes,        // [B,D]
    const float* __restrict__ in_embed,   // [V,E]
    const float* __restrict__ node_embed, // [N,E]
    float* __restrict__ out)              // [B]
{
    const int lane = threadIdx.x & 63;
    const int sl   = lane & 31;          // sub-lane within half
    const bool hi  = lane >= 32;         // which half
    // b is identical across the wave's 64 lanes; readfirstlane moves it to
    // an SGPR so the index loads below select as scalar (SMEM) loads.
    int b = (int)(blockIdx.x << 2) + (int)(threadIdx.x >> 6);
    b = __builtin_amdgcn_readfirstlane(b);

    // ---- index preload: wave-uniform -> scalar loads, land in SGPRs ----
    const int* __restrict__ cp = ctx   + b * Cn;
    const int* __restrict__ np = nodes + b * Dn;
    const int* __restrict__ kp = codes + b * Dn;
    int cidx[Cn];
    #pragma unroll
    for (int k = 0; k < Cn; ++k) cidx[k] = cp[k];
    int nidx[Dn];
    #pragma unroll
    for (int k = 0; k < Dn; ++k) nidx[k] = np[k];
    int code[Dn];
    #pragma unroll
    for (int k = 0; k < Dn; ++k) code[k] = kp[k];

    const float4* __restrict__ in4 = (const float4*)in_embed;    // 32 f4/row
    const float4* __restrict__ ne4 = (const float4*)node_embed;

    // ---- issue ALL 14 gathers before consuming any (MLP = 14) ----------
    // halves gather DIFFERENT rows in the same instruction:
    //   half 0 handles even c/d, half 1 odd.
    float4 e[Cn / 2];
    #pragma unroll
    for (int k = 0; k < Cn / 2; ++k) {
        const int idx = hi ? cidx[2 * k + 1] : cidx[2 * k];
        e[k] = in4[(size_t)idx * 32 + sl];
    }
    float4 u[Dn / 2];
    #pragma unroll
    for (int i = 0; i < Dn / 2; ++i) {
        const int idx = hi ? nidx[2 * i + 1] : nidx[2 * i];
        u[i] = ne4[(size_t)idx * 32 + sl];
    }

    // ---- v = mean of 10 context rows (same add order as R3) ------------
    float4 vs = make_float4(0.f, 0.f, 0.f, 0.f);
    #pragma unroll
    for (int k = 0; k < Cn / 2; ++k) {
        vs.x += e[k].x; vs.y += e[k].y; vs.z += e[k].z; vs.w += e[k].w;
    }
    // combine halves: after this both halves hold the full context sum
    vs.x += __shfl_xor(vs.x, 32, 64);
    vs.y += __shfl_xor(vs.y, 32, 64);
    vs.z += __shfl_xor(vs.z, 32, 64);
    vs.w += __shfl_xor(vs.w, 32, 64);
    float4 v;
    v.x = vs.x * (1.0f / Cn); v.y = vs.y * (1.0f / Cn);
    v.z = vs.z * (1.0f / Cn); v.w = vs.w * (1.0f / Cn);

    // ---- 18 dots: half 0 -> even d, half 1 -> odd d (9 each) -----------
    float pd[Dn / 2];
    #pragma unroll
    for (int i = 0; i < Dn / 2; ++i) {
        pd[i] = u[i].x * v.x + u[i].y * v.y + u[i].z * v.z + u[i].w * v.w;
    }

    // 5-level butterfly within each 32-lane half (masks never cross halves)
    #pragma unroll
    for (int i = 0; i < Dn / 2; ++i) {
        #pragma unroll
        for (int m = 16; m >= 1; m >>= 1)
            pd[i] += __shfl_xor(pd[i], m, 64);
    }

    // ---- loss: 9 transcendental passes, halves do different d in lockstep
    float loss = 0.f;
    #pragma unroll
    for (int i = 0; i < Dn / 2; ++i) {
        const int cd = hi ? code[2 * i + 1] : code[2 * i];
        // Literal fp32 reference semantics:
        float s = 1.0f / (1.0f + expf(-pd[i]));
        float p = (cd == 1) ? s : 1.0f - s;
        loss -= logf(p + EPS);
    }
    // half 0 holds even-d terms, half 1 odd-d terms
    loss += __shfl_xor(loss, 32, 64);

    if (lane == 0) out[b] = loss;
}

extern "C" void kernel_launch(void* const* d_in, const int* in_sizes, int n_in,
                              void* d_out, int out_size, void* d_ws, size_t ws_size,
                              hipStream_t stream) {
    const int*   ctx        = (const int*)d_in[0];
    const int*   path_nodes = (const int*)d_in[1];
    const int*   codes      = (const int*)d_in[2];
    const float* in_embed   = (const float*)d_in[3];
    const float* node_embed = (const float*)d_in[4];
    float*       out        = (float*)d_out;

    dim3 grid(Bn / 4);
    dim3 block(256);
    cbow_hs_kernel<<<grid, block, 0, stream>>>(ctx, path_nodes, codes,
                                               in_embed, node_embed, out);
}